// Round 2
// baseline (146.925 us; speedup 1.0000x reference)
//
#include <hip/hip_runtime.h>
#include <hip/hip_fp16.h>

// ---------------------------------------------------------------------------
// B=8, N=1024, F=320, H=5 (heads collapse: at = (Q·K^T)/8)
// R17: fused_attn v2 — barrier-free streaming phases.
//   Both GEMM B-operands (K_b, hW_b) are NT row-major over k, so the MFMA
//   B-fragment is a contiguous 16B global load per lane (quads of one lrow
//   cover a full 64B line). Drop ALL LDS staging / double-buffering /
//   barriers in phases A and C: Q lives in registers (20 half8), K/hW are
//   loaded straight to VGPRs inside fully-unrolled MFMA loops (compiler
//   pipelines with counted vmcnt). LDS holds only P (64 KB) + hist (8 KB);
//   the f32 k-split reduction aliases P after its last read.
//   Numerics: identical k-ascending accumulation chains -> bit-identical.
// Pipeline: prep_all -> g1_combined (hWT + Q/K) -> fused_attn.
// ---------------------------------------------------------------------------

typedef __attribute__((ext_vector_type(8))) _Float16 half8;
typedef __attribute__((ext_vector_type(4))) float f32x4;

// ---- stage a (nrow16*16) x 32 fp16 tile into LDS, K-chunk XOR-swizzled -----
// (used by g1_combined only)
__device__ __forceinline__ void stage_tile(const __half* g, __half* lds,
                                           int nrow16, int ld, int wave, int lane) {
    const int r = lane >> 2;
    const int c = ((lane & 3) ^ ((lane >> 3) & 3)) * 8;  // swizzled chunk
    for (int i = wave; i < nrow16; i += 4) {
        const __half* src = g + (long)(i * 16 + r) * ld + c;
        __builtin_amdgcn_global_load_lds(
            (const __attribute__((address_space(1))) unsigned int*)src,
            (__attribute__((address_space(3))) unsigned int*)(lds + i * 512),
            16, 0, 0);
    }
}

// ---------------------------------------------------------------------------
// 128x128 NT fp16 dbuf GEMM body, CH=2 (BK=64), runtime bx/by. K=320 -> 5
// barrier rounds. Buffer: [A c0][A c1][B c0][B c1], 4096 halfs each.
// EPI 1: +bqk, deinterleave -> Q,K fp16.  EPI 2: fp16 store (hWT, ldc=8192).
// ---------------------------------------------------------------------------
template <int EPI>
__device__ __forceinline__ void gemm_body(
    const __half* __restrict__ A, const __half* __restrict__ B,
    void* __restrict__ C, void* __restrict__ C2, const float* __restrict__ bias,
    int lda, int ldb, int ldc, int bx, int by, __half* smem)
{
    constexpr int BUF = 16384;  // (4096+4096)*2 halfs
    const int tid  = threadIdx.x;
    const int lane = tid & 63;
    const int wave = tid >> 6;
    const int wm   = wave >> 1;
    const int wn   = wave & 1;

    const __half* Ab = A + (long)by * 128 * lda;
    const __half* Bb = B + (long)bx * 128 * ldb;

    f32x4 acc[4][4];
    #pragma unroll
    for (int i = 0; i < 4; ++i)
        #pragma unroll
        for (int j = 0; j < 4; ++j) acc[i][j] = (f32x4){0.f, 0.f, 0.f, 0.f};

    const int lrow = lane & 15;
    const int quad = lane >> 4;
    const int swz = (quad ^ ((lrow >> 1) & 3)) * 8;

    #pragma unroll
    for (int c = 0; c < 2; ++c) {
        stage_tile(Ab + c * 32, smem + c * 4096, 8, lda, wave, lane);
        stage_tile(Bb + c * 32, smem + 8192 + c * 4096, 8, ldb, wave, lane);
    }

    for (int it = 0; it < 5; ++it) {
        __syncthreads();
        if (it + 1 < 5) {
            __half* nb = smem + ((it + 1) & 1) * BUF;
            const int k1 = (it + 1) * 64;
            #pragma unroll
            for (int c = 0; c < 2; ++c) {
                stage_tile(Ab + k1 + c * 32, nb + c * 4096, 8, lda, wave, lane);
                stage_tile(Bb + k1 + c * 32, nb + 8192 + c * 4096, 8, ldb, wave, lane);
            }
        }
        const __half* buf = smem + (it & 1) * BUF;
        #pragma unroll
        for (int c = 0; c < 2; ++c) {
            const __half* pA = buf + c * 4096 + (wm * 64 + lrow) * 32 + swz;
            const __half* pB = buf + 8192 + c * 4096 + (wn * 64 + lrow) * 32 + swz;
            half8 ah[4], bh[4];
            #pragma unroll
            for (int mt = 0; mt < 4; ++mt) ah[mt] = *(const half8*)(pA + mt * 512);
            #pragma unroll
            for (int nt = 0; nt < 4; ++nt) bh[nt] = *(const half8*)(pB + nt * 512);
            #pragma unroll
            for (int mt = 0; mt < 4; ++mt)
                #pragma unroll
                for (int nt = 0; nt < 4; ++nt)
                    acc[mt][nt] = __builtin_amdgcn_mfma_f32_16x16x32_f16(
                        ah[mt], bh[nt], acc[mt][nt], 0, 0, 0);
        }
    }

    const int row_base = by * 128 + wm * 64;
    const int col_base = bx * 128 + wn * 64;
    #pragma unroll
    for (int mt = 0; mt < 4; ++mt)
        #pragma unroll
        for (int nt = 0; nt < 4; ++nt)
            #pragma unroll
            for (int r = 0; r < 4; ++r) {
                const int row = row_base + mt * 16 + quad * 4 + r;
                const int col = col_base + nt * 16 + lrow;
                const float v = acc[mt][nt][r];
                if (EPI == 1) {
                    const float val = v + bias[col];
                    const long idx = (long)row * 320 + (col >> 1);
                    if (col & 1) ((__half*)C2)[idx] = __float2half(val);
                    else         ((__half*)C)[idx]  = __float2half(val);
                } else {
                    ((__half*)C)[(long)row * ldc + col] = __float2half(v);
                }
            }
}

// ---- combined: blocks 0..191 do hWT (64x3 tiles); 192..511 do G1' (5x64) ---
__global__ __launch_bounds__(256) void g1_combined(
    const __half* __restrict__ h16, const __half* __restrict__ wTp,
    const __half* __restrict__ WqkT, __half* __restrict__ hWT,
    __half* __restrict__ Q, __half* __restrict__ Kb,
    const float* __restrict__ bqk)
{
    __shared__ __half smem[2 * 16384];
    const int bx = blockIdx.x;
    if (bx < 192) {
        gemm_body<2>(wTp, h16, hWT, nullptr, nullptr,
                     320, 320, 8192, bx % 64, bx / 64, smem);
    } else {
        const int b = bx - 192;
        gemm_body<1>(h16, WqkT, Q, Kb, bqk,
                     320, 320, 320, b % 5, b / 5, smem);
    }
}

// ---- fused prep: h->fp16 (blocks 0..2559) | Wqk^T | weight^T --------------
__global__ __launch_bounds__(256) void prep_all(
    const float* __restrict__ h, ushort4* __restrict__ h16,
    const float* __restrict__ Wqk, __half* __restrict__ WqkT,
    const float* __restrict__ weight, __half* __restrict__ wTp)
{
    const int bx = blockIdx.x;
    if (bx < 2560) {
        const int i = bx * 256 + threadIdx.x;
        const float4 v = ((const float4*)h)[i];
        ushort4 o;
        o.x = __half_as_ushort(__float2half(v.x));
        o.y = __half_as_ushort(__float2half(v.y));
        o.z = __half_as_ushort(__float2half(v.z));
        o.w = __half_as_ushort(__float2half(v.w));
        h16[i] = o;
        return;
    }
    __shared__ float t[32][33];
    const float* src;
    __half* dst;
    int ldS, ldT, c0, r0;
    if (bx < 2760) {
        const int b = bx - 2560;
        src = Wqk; dst = WqkT; ldS = 640; ldT = 320;
        c0 = (b % 20) * 32; r0 = (b / 20) * 32;
    } else {
        const int b = bx - 2760;
        src = weight; dst = wTp; ldS = 320; ldT = 320;
        c0 = (b % 10) * 32; r0 = (b / 10) * 32;
    }
    const int lx = threadIdx.x & 31, ly = threadIdx.x >> 5;
    #pragma unroll
    for (int i = 0; i < 4; ++i)
        t[ly + 8 * i][lx] = src[(long)(r0 + ly + 8 * i) * ldS + c0 + lx];
    __syncthreads();
    #pragma unroll
    for (int i = 0; i < 4; ++i)
        dst[(long)(c0 + ly + 8 * i) * ldT + r0 + lx] = __float2half(t[lx][ly + 8 * i]);
}

// ---------------------------------------------------------------------------
// fused_attn v2: per block = 32 query rows of one batch (batch = bid&7).
// Phase A: P = 0.125 * Q_rows @ K_b^T. Q in regs (20 half8); K B-frags
//   loaded per-lane straight from global (16B, full-line coalesced);
//   NO LDS staging, NO barriers. Wave w owns cols [w*128, w*128+128).
// Phase B: exact 171st-largest per row (2-pass radix) + softmax in LDS.
// Phase C: out = attn @ hW_b + bias. hW B-frags straight from global;
//   A-frags from P (ds_read_b128, XOR-swizzled). 2-way k-split across wave
//   halves; f32 reduction aliases P after its final read.
// LDS: P 64 KB + hist 8 KB = 72 KB.
// ---------------------------------------------------------------------------
__global__ __launch_bounds__(512, 2) void fused_attn(
    const __half* __restrict__ Q, const __half* __restrict__ Kmat,
    const __half* __restrict__ hWT, const float* __restrict__ bias,
    float* __restrict__ out)
{
    __shared__ __half P[32768];      // 32 x 1024 fp16, idx ^= (row&7)<<3
    __shared__ int hist[8][256];

    const int tid  = threadIdx.x;
    const int lane = tid & 63;
    const int wave = tid >> 6;
    const int lrow = lane & 15;
    const int quad = lane >> 4;

    const int b  = blockIdx.x & 7;          // batch -> XCD affinity
    const int r0 = (blockIdx.x >> 3) * 32;  // query-row base

    const __half* Qb = Q    + (long)(b * 1024 + r0) * 320;
    const __half* Kb = Kmat + (long)b * 327680;
    const __half* Wb = hWT  + (long)b * 1024;

    // ---------------- Phase A: P = 0.125 * Q @ K^T ----------------
    // A-frags: lane (lrow,quad) holds Q[mi*16+lrow][kc*32 + quad*8 ..+7]
    half8 qreg[10][2];
    #pragma unroll
    for (int kc = 0; kc < 10; ++kc)
        #pragma unroll
        for (int mi = 0; mi < 2; ++mi)
            qreg[kc][mi] = *(const half8*)(Qb + (long)(mi * 16 + lrow) * 320
                                           + kc * 32 + quad * 8);

    const __half* Kw = Kb + (long)(wave * 128 + lrow) * 320 + quad * 8;
    #pragma unroll
    for (int cg = 0; cg < 2; ++cg) {           // two 64-col groups
        f32x4 acc[4][2];
        #pragma unroll
        for (int i = 0; i < 4; ++i)
            #pragma unroll
            for (int j = 0; j < 2; ++j) acc[i][j] = (f32x4){0.f, 0.f, 0.f, 0.f};
        #pragma unroll
        for (int kc = 0; kc < 10; ++kc) {
            half8 bh[4];
            #pragma unroll
            for (int cb = 0; cb < 4; ++cb)
                bh[cb] = *(const half8*)(Kw + (long)(cg * 64 + cb * 16) * 320
                                         + kc * 32);
            #pragma unroll
            for (int cb = 0; cb < 4; ++cb)
                #pragma unroll
                for (int mi = 0; mi < 2; ++mi)
                    acc[cb][mi] = __builtin_amdgcn_mfma_f32_16x16x32_f16(
                        qreg[kc][mi], bh[cb], acc[cb][mi], 0, 0, 0);
        }
        #pragma unroll
        for (int cb = 0; cb < 4; ++cb)
            #pragma unroll
            for (int mi = 0; mi < 2; ++mi)
                #pragma unroll
                for (int rr = 0; rr < 4; ++rr) {
                    const int row = mi * 16 + quad * 4 + rr;
                    const int col = wave * 128 + cg * 64 + cb * 16 + lrow;
                    P[((row << 10) + col) ^ ((row & 7) << 3)] =
                        __float2half(0.125f * acc[cb][mi][rr]);
                }
    }
    __syncthreads();

    // ---------------- Phase B: topk + softmax in LDS ----------------
    for (int j = 0; j < 4; ++j) {
        const int row  = wave * 4 + j;
        const int key8 = (row & 7) << 3;
        const int base = (row << 10) + lane * 16;

        unsigned short vs[16];
        *(uint4*)&vs[0] = *(const uint4*)&P[base ^ key8];
        *(uint4*)&vs[8] = *(const uint4*)&P[(base + 8) ^ key8];

        unsigned key[16];
        #pragma unroll
        for (int i = 0; i < 16; ++i) {
            const unsigned u = vs[i];
            key[i] = (u & 0x8000u) ? ((~u) & 0xFFFFu) : (u | 0x8000u);
        }

        unsigned prefix = 0, pmask = 0;
        int kk = 171;

        #pragma unroll
        for (int pass = 0; pass < 2; ++pass) {
            const int shift = 8 - 8 * pass;
            *(int4*)&hist[wave][lane * 4] = make_int4(0, 0, 0, 0);
            __syncthreads();
            #pragma unroll
            for (int i = 0; i < 16; ++i) {
                if ((key[i] & pmask) == prefix)
                    atomicAdd(&hist[wave][(key[i] >> shift) & 255], 1);
            }
            __syncthreads();
            const int4 hh = *(const int4*)&hist[wave][lane * 4];
            const int s = hh.x + hh.y + hh.z + hh.w;
            int suf = s;
            #pragma unroll
            for (int off = 1; off < 64; off <<= 1) {
                const int o = __shfl_down(suf, off);
                if (lane + off < 64) suf += o;
            }
            const int cgt3 = suf - s;
            const int cgt2 = cgt3 + hh.w;
            const int cgt1 = cgt2 + hh.z;
            const int cgt0 = cgt1 + hh.y;
            int pick = 0x7FFFFFFF;
            if (cgt3 < kk && kk <= cgt3 + hh.w) pick = ((4 * lane + 3) << 16) | (kk - cgt3);
            if (cgt2 < kk && kk <= cgt2 + hh.z) pick = ((4 * lane + 2) << 16) | (kk - cgt2);
            if (cgt1 < kk && kk <= cgt1 + hh.y) pick = ((4 * lane + 1) << 16) | (kk - cgt1);
            if (cgt0 < kk && kk <= cgt0 + hh.x) pick = ((4 * lane + 0) << 16) | (kk - cgt0);
            #pragma unroll
            for (int off = 32; off > 0; off >>= 1) pick = min(pick, __shfl_xor(pick, off));
            const unsigned digit = (unsigned)(pick >> 16);
            kk = pick & 0xFFFF;
            prefix |= digit << shift;
            pmask  |= 0xFFu << shift;
            if (pass == 0) __syncthreads();
        }

        const unsigned short tu = (prefix & 0x8000u) ? (unsigned short)(prefix & 0x7FFFu)
                                                     : (unsigned short)((~prefix) & 0xFFFFu);
        const float thr = __half2float(__ushort_as_half(tu));

        float lg[16];
        float mx = -3.4e38f;
        #pragma unroll
        for (int i = 0; i < 16; ++i) {
            const float v = __half2float(__ushort_as_half(vs[i]));
            const float a = (v < thr) ? -1e-7f : v;
            lg[i] = a * (1.0f / 0.3f);
            mx = fmaxf(mx, lg[i]);
        }
        #pragma unroll
        for (int off = 32; off > 0; off >>= 1) mx = fmaxf(mx, __shfl_xor(mx, off));

        float e[16];
        float sum = 0.f;
        #pragma unroll
        for (int i = 0; i < 16; ++i) { e[i] = __expf(lg[i] - mx); sum += e[i]; }
        #pragma unroll
        for (int off = 32; off > 0; off >>= 1) sum += __shfl_xor(sum, off);
        const float inv = 1.0f / sum;

        unsigned short os[16];
        #pragma unroll
        for (int i = 0; i < 16; ++i) os[i] = __half_as_ushort(__float2half(e[i] * inv));
        *(uint4*)&P[base ^ key8]       = *(const uint4*)&os[0];
        *(uint4*)&P[(base + 8) ^ key8] = *(const uint4*)&os[8];
    }
    __syncthreads();

    // ---------------- Phase C: out = P @ hW_b + bias ----------------
    const int q4 = wave & 3;     // col quarter: 80 out-cols
    const int kh = wave >> 2;    // K half: 0 -> k<512, 1 -> k>=512

    f32x4 acc4[5][2];
    #pragma unroll
    for (int i = 0; i < 5; ++i)
        #pragma unroll
        for (int j = 0; j < 2; ++j) acc4[i][j] = (f32x4){0.f, 0.f, 0.f, 0.f};

    const __half* Wq = Wb + (long)(q4 * 80 + lrow) * 8192 + kh * 512 + quad * 8;
    #pragma unroll 4
    for (int t = 0; t < 16; ++t) {
        half8 bh[5];
        #pragma unroll
        for (int cf = 0; cf < 5; ++cf)
            bh[cf] = *(const half8*)(Wq + (long)cf * 16 * 8192 + t * 32);
        const int kk = kh * 512 + t * 32 + quad * 8;
        half8 ah[2];
        #pragma unroll
        for (int mi = 0; mi < 2; ++mi) {
            const int row = mi * 16 + lrow;
            ah[mi] = *(const half8*)&P[((row << 10) + kk) ^ ((row & 7) << 3)];
        }
        #pragma unroll
        for (int cf = 0; cf < 5; ++cf)
            #pragma unroll
            for (int mi = 0; mi < 2; ++mi)
                acc4[cf][mi] = __builtin_amdgcn_mfma_f32_16x16x32_f16(
                    ah[mi], bh[cf], acc4[cf][mi], 0, 0, 0);
    }

    __syncthreads();                 // all P reads done; P region now dead
    float* const red = (float*)P;    // 32 x 320 f32 = 40 KB, aliases P
    if (kh == 1) {
        #pragma unroll
        for (int cf = 0; cf < 5; ++cf)
            #pragma unroll
            for (int mi = 0; mi < 2; ++mi)
                #pragma unroll
                for (int rr = 0; rr < 4; ++rr)
                    red[(mi * 16 + quad * 4 + rr) * 320 + q4 * 80 + cf * 16 + lrow] =
                        acc4[cf][mi][rr];
    }
    __syncthreads();
    if (kh == 0) {
        #pragma unroll
        for (int cf = 0; cf < 5; ++cf)
            #pragma unroll
            for (int mi = 0; mi < 2; ++mi)
                #pragma unroll
                for (int rr = 0; rr < 4; ++rr) {
                    const int row = mi * 16 + quad * 4 + rr;
                    const int col = q4 * 80 + cf * 16 + lrow;
                    out[(long)(b * 1024 + r0 + row) * 320 + col] =
                        acc4[cf][mi][rr] + red[row * 320 + col] + bias[col];
                }
    }
}

extern "C" void kernel_launch(void* const* d_in, const int* in_sizes, int n_in,
                              void* d_out, int out_size, void* d_ws, size_t ws_size,
                              hipStream_t stream) {
    (void)in_sizes; (void)n_in; (void)out_size; (void)ws_size;

    const float* h      = (const float*)d_in[0];  // 8x1024x320
    const float* Wqk    = (const float*)d_in[1];  // 320x640
    const float* bqk    = (const float*)d_in[2];  // 640
    const float* weight = (const float*)d_in[3];  // 320x320
    const float* bias   = (const float*)d_in[4];  // 320
    float* out = (float*)d_out;                   // 8192x320

    // workspace layout
    char* p = (char*)d_ws;
    __half* h16  = (__half*)p; p += 2621440L * 2;        // 5 MB
    __half* Q    = (__half*)p; p += 2621440L * 2;        // 5 MB
    __half* Kb   = (__half*)p; p += 2621440L * 2;        // 5 MB
    __half* WqkT = (__half*)p; p += 640L * 320 * 2;      // 400 KB
    __half* wTp  = (__half*)p; p += 384L * 320 * 2;      // padded to 384 rows
    __half* hWT  = (__half*)p; p += 384L * 8192 * 2;     // 6 MB (incl pad rows)

    // --- prep (1 launch): h->fp16, WqkT, wTp ---
    prep_all<<<2860, 256, 0, stream>>>(h, (ushort4*)h16, Wqk, WqkT, weight, wTp);

    // --- combined: hWT (192 blocks) + G1' Q/K (320 blocks), BK=64 ---
    g1_combined<<<512, 256, 0, stream>>>(h16, wTp, WqkT, hWT, Q, Kb, bqk);

    // --- fused G2 + topk/softmax + G4 (barrier-free streaming phases) ---
    fused_attn<<<256, 512, 0, stream>>>(Q, Kb, hWT, bias, out);
}